// Round 12
// baseline (661.529 us; speedup 1.0000x reference)
//
#include <hip/hip_runtime.h>
#include <hip/hip_bf16.h>
#include <math.h>

#define NODES 50000
#define EDGES 800000
#define EP    850000      // EDGES + NODES self loops
#define INCH  64
#define HIDD  96
#define NHEAD 4
#define CHD   24
#define NLAY  4
#define NGRF  1024
#define BNEPS 1e-5f
#define NT2   (2 * NODES)   // concatenated A|B count arrays
#define NB2   98            // ceil(NT2/1024)
#define HALF  25000         // src partition boundary

__device__ __forceinline__ float elu1(float v) { return v > 0.f ? v : __expf(v) - 1.f; }

__device__ __forceinline__ unsigned short f2bf(float f) {   // RNE, matches HW
    unsigned u = __float_as_uint(f);
    return (unsigned short)((u + 0x7fffu + ((u >> 16) & 1u)) >> 16);
}

__device__ __forceinline__ float rl_f(float v, int l) {     // readlane broadcast (uniform l)
    return __int_as_float(__builtin_amdgcn_readlane(__float_as_int(v), l));
}

__device__ __forceinline__ float bnorm(float a, const float* __restrict__ bg,
                                       const float* __restrict__ rm, const float* __restrict__ rv,
                                       const float* __restrict__ gamma, const float* __restrict__ beta,
                                       int ch) {
    float hn = a + bg[ch];
    return (hn - rm[ch]) / sqrtf(rv[ch] + BNEPS) * gamma[ch] + beta[ch];
}

__device__ __forceinline__ void edge_sd(int e, const int* __restrict__ S,
                                        const int* __restrict__ D, int& s, int& d) {
    if (e < EDGES) { s = S[e]; d = D[e]; } else { s = e - EDGES; d = s; }
}

// ---------------- CSR build, src-half partitioned (once per call) ----------------

__global__ __launch_bounds__(256) void k_count(const int* __restrict__ S, const int* __restrict__ D,
                                               int* __restrict__ cnt2) {
    int e = blockIdx.x * blockDim.x + threadIdx.x;
    if (e >= EP) return;
    int s, d; edge_sd(e, S, D, s, d);
    atomicAdd(&cnt2[(s < HALF) ? d : NODES + d], 1);
}

__global__ __launch_bounds__(1024) void k_scan1(const int* __restrict__ cnt,
                                                int* __restrict__ off, int* __restrict__ bsum) {
    __shared__ int sd[1024];
    int t = threadIdx.x;
    int i = blockIdx.x * 1024 + t;
    int v = (i < NT2) ? cnt[i] : 0;
    sd[t] = v; __syncthreads();
    for (int o = 1; o < 1024; o <<= 1) {
        int tv = (t >= o) ? sd[t - o] : 0;
        __syncthreads();
        sd[t] += tv; __syncthreads();
    }
    if (i < NT2) off[i] = sd[t] - v;             // exclusive within block
    if (t == 1023) bsum[blockIdx.x] = sd[1023];
}

__global__ void k_scan2(int* __restrict__ bsum, int* __restrict__ off) {
    if (threadIdx.x == 0 && blockIdx.x == 0) {
        int run = 0;
        for (int b = 0; b < NB2; ++b) { int tv = bsum[b]; bsum[b] = run; run += tv; }
        off[NT2] = run;                          // == EP
    }
}

__global__ __launch_bounds__(1024) void k_scan3(int* __restrict__ off, const int* __restrict__ bsum,
                                                int* __restrict__ cursor) {
    int i = blockIdx.x * 1024 + threadIdx.x;
    if (i >= NT2) return;
    int o = off[i] + bsum[blockIdx.x];
    off[i] = o;
    cursor[i] = o;
}

__global__ __launch_bounds__(256) void k_scatter(const int* __restrict__ S, const int* __restrict__ D,
                                                 int* __restrict__ cursor, int* __restrict__ csr_src) {
    int e = blockIdx.x * blockDim.x + threadIdx.x;
    if (e >= EP) return;
    int s, d; edge_sd(e, S, D, s, d);
    int pos = atomicAdd(&cursor[(s < HALF) ? d : NODES + d], 1);
    csr_src[pos] = s;
}

// ---------------- dense node kernels ----------------

// h0 = elu(x @ W_in + b_in). W staged in LDS; lane=node, wave-uniform channel group.
__global__ __launch_bounds__(256) void k_in_proj(const float* __restrict__ x,
                                                 const float* __restrict__ W,
                                                 const float* __restrict__ b,
                                                 float* __restrict__ h) {
    __shared__ float Wl[INCH * HIDD];   // 24 KB
    int tid = threadIdx.x;
    for (int i = tid; i < INCH * HIDD / 4; i += 256)
        ((float4*)Wl)[i] = ((const float4*)W)[i];
    __syncthreads();

    int node = blockIdx.x * 64 + (tid & 63);
    if (node >= NODES) return;
    int cbase = (tid >> 6) * CHD;       // 0,24,48,72 (wave-uniform)
    const float* __restrict__ xr = x + (size_t)node * INCH;

    float acc[CHD];
#pragma unroll
    for (int j = 0; j < CHD; ++j) acc[j] = b[cbase + j];

    for (int k0 = 0; k0 < INCH; k0 += 4) {
        float4 xv = *(const float4*)(xr + k0);
        const float xvv[4] = {xv.x, xv.y, xv.z, xv.w};
#pragma unroll
        for (int kk = 0; kk < 4; ++kk) {
#pragma unroll
            for (int j4 = 0; j4 < CHD; j4 += 4) {
                float4 wv = *(const float4*)(&Wl[(k0 + kk) * HIDD + cbase + j4]);
                acc[j4 + 0] = fmaf(xvv[kk], wv.x, acc[j4 + 0]);
                acc[j4 + 1] = fmaf(xvv[kk], wv.y, acc[j4 + 1]);
                acc[j4 + 2] = fmaf(xvv[kk], wv.z, acc[j4 + 2]);
                acc[j4 + 3] = fmaf(xvv[kk], wv.w, acc[j4 + 3]);
            }
        }
    }
    float* hrow = h + (size_t)node * HIDD + cbase;
#pragma unroll
    for (int j = 0; j < CHD; ++j) hrow[j] = elu1(acc[j]);
}

// hp(bf16-packed) = h @ Wg[i]; fused per-head attention dots (cgroup == head).
// Wg staged in LDS (36 KB) -> uniform-address broadcast ds_read_b128.
__global__ __launch_bounds__(256) void k_proj(const float* __restrict__ h,
                                              const float* __restrict__ W,
                                              const float* __restrict__ asrc,
                                              const float* __restrict__ adst,
                                              unsigned* __restrict__ hpb,   // [N][48] packed bf16x2
                                              float* __restrict__ as_,
                                              float* __restrict__ ad_) {
    __shared__ float Wl[HIDD * HIDD];   // 36 KB
    int tid = threadIdx.x;
    for (int i = tid; i < HIDD * HIDD / 4; i += 256)
        ((float4*)Wl)[i] = ((const float4*)W)[i];
    __syncthreads();

    int node = blockIdx.x * 64 + (tid & 63);
    if (node >= NODES) return;
    int head = tid >> 6;                 // 0..3 (wave-uniform)
    int cbase = head * CHD;
    const float* __restrict__ hr = h + (size_t)node * HIDD;

    float acc[CHD] = {};
    for (int k0 = 0; k0 < HIDD; k0 += 4) {
        float4 hv = *(const float4*)(hr + k0);
        const float hvv[4] = {hv.x, hv.y, hv.z, hv.w};
#pragma unroll
        for (int kk = 0; kk < 4; ++kk) {
#pragma unroll
            for (int j4 = 0; j4 < CHD; j4 += 4) {
                float4 wv = *(const float4*)(&Wl[(k0 + kk) * HIDD + cbase + j4]);
                acc[j4 + 0] = fmaf(hvv[kk], wv.x, acc[j4 + 0]);
                acc[j4 + 1] = fmaf(hvv[kk], wv.y, acc[j4 + 1]);
                acc[j4 + 2] = fmaf(hvv[kk], wv.z, acc[j4 + 2]);
                acc[j4 + 3] = fmaf(hvv[kk], wv.w, acc[j4 + 3]);
            }
        }
    }
    unsigned* orow = hpb + (size_t)node * (HIDD / 2) + cbase / 2;
#pragma unroll
    for (int j = 0; j < CHD; j += 2)
        orow[j / 2] = (unsigned)f2bf(acc[j]) | ((unsigned)f2bf(acc[j + 1]) << 16);

    const float* __restrict__ s = asrc + head * CHD;
    const float* __restrict__ d = adst + head * CHD;
    float sa = 0.f, da = 0.f;
#pragma unroll
    for (int j = 0; j < CHD; ++j) { sa = fmaf(acc[j], s[j], sa); da = fmaf(acc[j], d[j], da); }
    as_[node * NHEAD + head] = sa;
    ad_[node * NHEAD + head] = da;
}

// ---------------- fused edge phase: 2 nodes/wave, 2 src-half sweeps ----------------
// alpha = exp(leaky(as+ad)) / z (max-sub cancels in p/z; |ev| << 88, no overflow).
// All waves sweep src-half A (hpb rows < HALF, ~4.8 MB ~ L2-resident) then half B.

__device__ __forceinline__ void half_sweep(int ca, int end0, int cb, int end1,
                                           const int* __restrict__ csr,
                                           const float* __restrict__ as_,
                                           const unsigned* __restrict__ hpb,
                                           float* __restrict__ plds, int wb,
                                           int lane, int hd, int slot, int hh, bool gl,
                                           float adv0, float adv1,
                                           float& a00, float& a01, float& a10, float& a11,
                                           float& zA, float& zB) {
    while (ca < end0 || cb < end1) {
        bool doA = ca < end0, doB = cb < end1;      // wave-uniform
        int sA = 0, sB = 0;
        if (doA) {
            int i = ca + slot, ii = min(i, end0 - 1);
            sA = csr[ii];
            float ev = as_[sA * NHEAD + hd] + adv0;
            ev = ev > 0.f ? ev : 0.2f * ev;
            float p = (i < end0) ? __expf(ev) : 0.f;
            zA += p;
            plds[wb + lane] = p;
        }
        if (doB) {
            int i = cb + slot, ii = min(i, end1 - 1);
            sB = csr[ii];
            float ev = as_[sB * NHEAD + hd] + adv1;
            ev = ev > 0.f ? ev : 0.2f * ev;
            float p = (i < end1) ? __expf(ev) : 0.f;
            zB += p;
            plds[wb + 64 + lane] = p;
        }
        if (doA) {
#pragma unroll
            for (int j = 0; j < 16; ++j) {
                int sv = __builtin_amdgcn_readlane(sA, j * 4);
                float al = plds[wb + j * 4 + hh];
                if (gl) {
                    unsigned u = (hpb + (size_t)sv * (HIDD / 2))[lane];
                    a00 = fmaf(__uint_as_float(u << 16),         al, a00);
                    a01 = fmaf(__uint_as_float(u & 0xffff0000u), al, a01);
                }
            }
            ca += 16;
        }
        if (doB) {
#pragma unroll
            for (int j = 0; j < 16; ++j) {
                int sv = __builtin_amdgcn_readlane(sB, j * 4);
                float al = plds[wb + 64 + j * 4 + hh];
                if (gl) {
                    unsigned u = (hpb + (size_t)sv * (HIDD / 2))[lane];
                    a10 = fmaf(__uint_as_float(u << 16),         al, a10);
                    a11 = fmaf(__uint_as_float(u & 0xffff0000u), al, a11);
                }
            }
            cb += 16;
        }
    }
}

__global__ __launch_bounds__(256) void k_edge(const int* __restrict__ off2,
                                              const int* __restrict__ csr,
                                              const float* __restrict__ as_,
                                              const float* __restrict__ ad_,
                                              const unsigned* __restrict__ hpb,
                                              const float* __restrict__ bg,
                                              const float* __restrict__ gamma,
                                              const float* __restrict__ beta,
                                              const float* __restrict__ rm,
                                              const float* __restrict__ rv,
                                              float* __restrict__ h,
                                              const int* __restrict__ batch,
                                              float* __restrict__ pooled) {
    __shared__ float plds[512];                     // per wave: 128 floats (2 nodes x 64)
    int tid = threadIdx.x;
    int lane = tid & 63;
    int n0 = __builtin_amdgcn_readfirstlane(blockIdx.x * 8 + (tid >> 6) * 2);  // exact grid
    int n1 = n0 + 1;

    int hd = lane & 3, slot = lane >> 2;            // alpha role: edge slot x head
    float adv0 = ad_[n0 * NHEAD + hd];
    float adv1 = ad_[n1 * NHEAD + hd];
    const int hh = (lane < 48) ? (lane / 12) : 0;   // gather role: head of channel pair
    const bool gl = (lane < 48);
    const int wb = (tid & 192) * 2;                 // wave's plds region (w*128)

    float a00 = 0.f, a01 = 0.f, a10 = 0.f, a11 = 0.f, zA = 0.f, zB = 0.f;
    // half A: src < HALF
    half_sweep(off2[n0], off2[n0 + 1], off2[n1], off2[n1 + 1],
               csr, as_, hpb, plds, wb, lane, hd, slot, hh, gl,
               adv0, adv1, a00, a01, a10, a11, zA, zB);
    // half B: src >= HALF
    half_sweep(off2[NODES + n0], off2[NODES + n0 + 1], off2[NODES + n1], off2[NODES + n1 + 1],
               csr, as_, hpb, plds, wb, lane, hd, slot, hh, gl,
               adv0, adv1, a00, a01, a10, a11, zA, zB);

    // z totals per head for both nodes
#pragma unroll
    for (int o = 4; o < 64; o <<= 1) { zA += __shfl_xor(zA, o); zB += __shfl_xor(zB, o); }
    float za0 = rl_f(zA, 0), za1 = rl_f(zA, 1), za2 = rl_f(zA, 2), za3 = rl_f(zA, 3);
    float zb0 = rl_f(zB, 0), zb1 = rl_f(zB, 1), zb2 = rl_f(zB, 2), zb3 = rl_f(zB, 3);
    float zAl = (hh & 1) ? za1 : za0, zAh = (hh & 1) ? za3 : za2;
    float zBl = (hh & 1) ? zb1 : zb0, zBh = (hh & 1) ? zb3 : zb2;
    float zhA = (hh & 2) ? zAh : zAl;
    float zhB = (hh & 2) ? zBh : zBl;

    int g0 = batch[n0], g1 = batch[n1];             // uniform (s_load)
    if (gl) {
        float izA = 1.f / zhA, izB = 1.f / zhB;     // z > 0 guaranteed (self-loop)
        a00 *= izA; a01 *= izA; a10 *= izB; a11 *= izB;
        int ch0 = 2 * lane, ch1 = ch0 + 1;
        float hn00 = bnorm(a00, bg, rm, rv, gamma, beta, ch0);
        float hn01 = bnorm(a01, bg, rm, rv, gamma, beta, ch1);
        float hn10 = bnorm(a10, bg, rm, rv, gamma, beta, ch0);
        float hn11 = bnorm(a11, bg, rm, rv, gamma, beta, ch1);
        float2 hv0 = *(float2*)(h + (size_t)n0 * HIDD + ch0);
        float2 hv1 = *(float2*)(h + (size_t)n1 * HIDD + ch0);
        hv0.x += elu1(hn00); hv0.y += elu1(hn01);
        hv1.x += elu1(hn10); hv1.y += elu1(hn11);
        *(float2*)(h + (size_t)n0 * HIDD + ch0) = hv0;
        *(float2*)(h + (size_t)n1 * HIDD + ch0) = hv1;
        if (g0 == g1) {                             // merged pooled atomics (common: sorted batch)
            atomicAdd(&pooled[g0 * HIDD + ch0], hv0.x + hv1.x);
            atomicAdd(&pooled[g0 * HIDD + ch1], hv0.y + hv1.y);
        } else {
            atomicAdd(&pooled[g0 * HIDD + ch0], hv0.x);
            atomicAdd(&pooled[g0 * HIDD + ch1], hv0.y);
            atomicAdd(&pooled[g1 * HIDD + ch0], hv1.x);
            atomicAdd(&pooled[g1 * HIDD + ch1], hv1.y);
        }
    }
}

// ---------------- per-graph MLP head ----------------

__global__ __launch_bounds__(128) void k_head(const float* __restrict__ pooled,
                                              const float* __restrict__ Wjk, const float* __restrict__ bjk,
                                              const float* __restrict__ Wh1, const float* __restrict__ bh1,
                                              const float* __restrict__ Wh2, const float* __restrict__ bh2,
                                              float* __restrict__ out) {
    __shared__ float pin[NLAY * HIDD];
    __shared__ float z1[HIDD];
    __shared__ float z2[HIDD];
    int g = blockIdx.x, tid = threadIdx.x;
    for (int idx = tid; idx < NLAY * HIDD; idx += blockDim.x) {
        int l = idx / HIDD, c = idx % HIDD;
        pin[idx] = pooled[(size_t)l * NGRF * HIDD + (size_t)g * HIDD + c];
    }
    __syncthreads();
    for (int c = tid; c < HIDD; c += blockDim.x) {
        float a = bjk[c];
        for (int k = 0; k < NLAY * HIDD; ++k) a = fmaf(pin[k], Wjk[k * HIDD + c], a);
        z1[c] = elu1(a);
    }
    __syncthreads();
    for (int c = tid; c < HIDD; c += blockDim.x) {
        float a = bh1[c];
#pragma unroll
        for (int k = 0; k < HIDD; ++k) a = fmaf(z1[k], Wh1[k * HIDD + c], a);
        z2[c] = fmaxf(a, 0.f);
    }
    __syncthreads();
    if (tid < 64) {
        float a = 0.f;
        for (int k = tid; k < HIDD; k += 64) a = fmaf(z2[k], Wh2[k], a);
#pragma unroll
        for (int o = 32; o > 0; o >>= 1) a += __shfl_down(a, o);
        if (tid == 0) out[g] = a + bh2[0];
    }
}

extern "C" void kernel_launch(void* const* d_in, const int* in_sizes, int n_in,
                              void* d_out, int out_size, void* d_ws, size_t ws_size,
                              hipStream_t stream) {
    const float* x     = (const float*)d_in[0];
    const int*   ei    = (const int*)d_in[1];
    const int*   batch = (const int*)d_in[2];
    const float* W_in  = (const float*)d_in[3];
    const float* b_in  = (const float*)d_in[4];
    const float* Wg    = (const float*)d_in[5];
    const float* att_s = (const float*)d_in[6];
    const float* att_d = (const float*)d_in[7];
    const float* bg    = (const float*)d_in[8];
    const float* gamma = (const float*)d_in[9];
    const float* beta  = (const float*)d_in[10];
    const float* rm    = (const float*)d_in[11];
    const float* rv    = (const float*)d_in[12];
    const float* Wjk   = (const float*)d_in[13];
    const float* bjk   = (const float*)d_in[14];
    const float* Wh1   = (const float*)d_in[15];
    const float* bh1   = (const float*)d_in[16];
    const float* Wh2   = (const float*)d_in[17];
    const float* bh2   = (const float*)d_in[18];
    float* out = (float*)d_out;

    const int* S = ei;
    const int* Dd = ei + EDGES;

    // workspace layout
    float* ws = (float*)d_ws;
    float*    h      = ws;                               // N*96 f32
    float*    as_    = h    + (size_t)NODES * HIDD;      // N*4
    float*    ad_    = as_  + (size_t)NODES * NHEAD;     // N*4
    float*    pooled = ad_  + (size_t)NODES * NHEAD;     // L*G*96
    unsigned* hpb    = (unsigned*)(pooled + (size_t)NLAY * NGRF * HIDD); // N*48 (bf16x2)
    int*      off2   = (int*)(hpb + (size_t)NODES * (HIDD / 2));  // 2N+1
    int*      cursor = off2   + NT2 + 1;                 // 2N
    int*      csr    = cursor + NT2;                     // EP
    int*      cnt2   = csr    + EP;                      // 2N
    int*      bsum   = cnt2   + NT2;                     // NB2

    hipMemsetAsync(pooled, 0, sizeof(float) * NLAY * NGRF * HIDD, stream);
    hipMemsetAsync(cnt2, 0, sizeof(int) * NT2, stream);

    const int TB = 256;
    int gE    = (EP + TB - 1) / TB;
    int gTile = (NODES + 63) / 64;   // 782 blocks, 64 nodes each
    int gEdge = NODES / 8;           // 6250 (exact: 8 nodes/block, 2 per wave)

    // src-half-partitioned CSR build (graph is identical across layers)
    k_count<<<gE, TB, 0, stream>>>(S, Dd, cnt2);
    k_scan1<<<NB2, 1024, 0, stream>>>(cnt2, off2, bsum);
    k_scan2<<<1, 64, 0, stream>>>(bsum, off2);
    k_scan3<<<NB2, 1024, 0, stream>>>(off2, bsum, cursor);
    k_scatter<<<gE, TB, 0, stream>>>(S, Dd, cursor, csr);

    k_in_proj<<<gTile, TB, 0, stream>>>(x, W_in, b_in, h);

    for (int i = 0; i < NLAY; ++i) {
        k_proj<<<gTile, TB, 0, stream>>>(h, Wg + (size_t)i * HIDD * HIDD,
                                         att_s + i * NHEAD * CHD, att_d + i * NHEAD * CHD,
                                         hpb, as_, ad_);
        k_edge<<<gEdge, TB, 0, stream>>>(off2, csr, as_, ad_, hpb,
                                         bg + i * HIDD, gamma + i * HIDD, beta + i * HIDD,
                                         rm + i * HIDD, rv + i * HIDD, h, batch,
                                         pooled + (size_t)i * NGRF * HIDD);
    }

    k_head<<<NGRF, 128, 0, stream>>>(pooled, Wjk, bjk, Wh1, bh1, Wh2, bh2, out);
}

// Round 13
// 553.271 us; speedup vs baseline: 1.1957x; 1.1957x over previous
//
#include <hip/hip_runtime.h>
#include <hip/hip_bf16.h>
#include <math.h>

#define NODES 50000
#define EDGES 800000
#define EP    850000      // EDGES + NODES self loops
#define INCH  64
#define HIDD  96
#define NHEAD 4
#define CHD   24
#define NLAY  4
#define NGRF  1024
#define BNEPS 1e-5f
#define NB    49          // ceil(NODES/1024)
#define HSTR  98          // hblk LDS row stride (float2-aligned, ~2-way banks)

__device__ __forceinline__ float elu1(float v) { return v > 0.f ? v : __expf(v) - 1.f; }

__device__ __forceinline__ unsigned short f2bf(float f) {   // RNE, matches HW
    unsigned u = __float_as_uint(f);
    return (unsigned short)((u + 0x7fffu + ((u >> 16) & 1u)) >> 16);
}

__device__ __forceinline__ float rl_f(float v, int l) {     // readlane broadcast (uniform l)
    return __int_as_float(__builtin_amdgcn_readlane(__float_as_int(v), l));
}

__device__ __forceinline__ float bnorm(float a, const float* __restrict__ bg,
                                       const float* __restrict__ rm, const float* __restrict__ rv,
                                       const float* __restrict__ gamma, const float* __restrict__ beta,
                                       int ch) {
    float hn = a + bg[ch];
    return (hn - rm[ch]) / sqrtf(rv[ch] + BNEPS) * gamma[ch] + beta[ch];
}

__device__ __forceinline__ void edge_sd(int e, const int* __restrict__ S,
                                        const int* __restrict__ D, int& s, int& d) {
    if (e < EDGES) { s = S[e]; d = D[e]; } else { s = e - EDGES; d = s; }
}

// ---------------- CSR build (once per call; graph is layer-invariant) ----------------

__global__ __launch_bounds__(256) void k_count(const int* __restrict__ S, const int* __restrict__ D,
                                               int* __restrict__ cnt) {
    int e = blockIdx.x * blockDim.x + threadIdx.x;
    if (e >= EP) return;
    int s, d; edge_sd(e, S, D, s, d);
    atomicAdd(&cnt[d], 1);
}

__global__ __launch_bounds__(1024) void k_scan1(const int* __restrict__ cnt,
                                                int* __restrict__ off, int* __restrict__ bsum) {
    __shared__ int sd[1024];
    int t = threadIdx.x;
    int i = blockIdx.x * 1024 + t;
    int v = (i < NODES) ? cnt[i] : 0;
    sd[t] = v; __syncthreads();
    for (int o = 1; o < 1024; o <<= 1) {
        int tv = (t >= o) ? sd[t - o] : 0;
        __syncthreads();
        sd[t] += tv; __syncthreads();
    }
    if (i < NODES) off[i] = sd[t] - v;           // exclusive within block
    if (t == 1023) bsum[blockIdx.x] = sd[1023];
}

// merged scan2+scan3: each block redundantly prefixes bsum (49 adds); off[N]=EP constant.
__global__ __launch_bounds__(1024) void k_scan3m(int* __restrict__ off, const int* __restrict__ bsum,
                                                 int* __restrict__ cursor) {
    int carry = 0;
    for (int b = 0; b < blockIdx.x; ++b) carry += bsum[b];   // uniform s_loads
    int i = blockIdx.x * 1024 + threadIdx.x;
    if (i < NODES) {
        int o = off[i] + carry;
        off[i] = o;
        cursor[i] = o;
    }
    if (i == 0) off[NODES] = EP;
}

__global__ __launch_bounds__(256) void k_scatter(const int* __restrict__ S, const int* __restrict__ D,
                                                 int* __restrict__ cursor, int* __restrict__ csr_src) {
    int e = blockIdx.x * blockDim.x + threadIdx.x;
    if (e >= EP) return;
    int s, d; edge_sd(e, S, D, s, d);
    int pos = atomicAdd(&cursor[d], 1);
    csr_src[pos] = s;
}

// ---------------- fused input proj + layer-0 proj ----------------
// Stage 1: h = elu(x@W_in + b_in) -> global h AND LDS hblk (cross-wave exchange).
// Stage 2: restage Wl with Wg0, hp0 = h @ Wg0 from LDS -> hpb/as_/ad_. Saves a dispatch
// and the 19 MB h re-read of a standalone k_proj.

__global__ __launch_bounds__(256) void k_in_proj_proj(const float* __restrict__ x,
                                                      const float* __restrict__ W_in,
                                                      const float* __restrict__ b_in,
                                                      const float* __restrict__ Wg0,
                                                      const float* __restrict__ asrc,
                                                      const float* __restrict__ adst,
                                                      float* __restrict__ h,
                                                      unsigned* __restrict__ hpb,
                                                      float* __restrict__ as_,
                                                      float* __restrict__ ad_) {
    __shared__ float Wl[HIDD * HIDD];       // 36 KB: W_in (24 KB) then Wg0
    __shared__ float hblk[64 * HSTR];       // 24.5 KB: h rows for the block's 64 nodes
    int tid = threadIdx.x;
    for (int i = tid; i < INCH * HIDD / 4; i += 256)
        ((float4*)Wl)[i] = ((const float4*)W_in)[i];
    __syncthreads();

    int lane = tid & 63;
    int node = blockIdx.x * 64 + lane;
    bool valid = node < NODES;
    int head = tid >> 6;                    // cgroup == head (wave-uniform)
    int cbase = head * CHD;

    // ---- stage 1: in_proj ----
    {
        const float* __restrict__ xr = x + (size_t)node * INCH;
        float acc[CHD];
#pragma unroll
        for (int j = 0; j < CHD; ++j) acc[j] = b_in[cbase + j];
        if (valid) {
            for (int k0 = 0; k0 < INCH; k0 += 4) {
                float4 xv = *(const float4*)(xr + k0);
                const float xvv[4] = {xv.x, xv.y, xv.z, xv.w};
#pragma unroll
                for (int kk = 0; kk < 4; ++kk) {
#pragma unroll
                    for (int j4 = 0; j4 < CHD; j4 += 4) {
                        float4 wv = *(const float4*)(&Wl[(k0 + kk) * HIDD + cbase + j4]);
                        acc[j4 + 0] = fmaf(xvv[kk], wv.x, acc[j4 + 0]);
                        acc[j4 + 1] = fmaf(xvv[kk], wv.y, acc[j4 + 1]);
                        acc[j4 + 2] = fmaf(xvv[kk], wv.z, acc[j4 + 2]);
                        acc[j4 + 3] = fmaf(xvv[kk], wv.w, acc[j4 + 3]);
                    }
                }
            }
        }
        float* hrow = h + (size_t)node * HIDD + cbase;
#pragma unroll
        for (int j = 0; j < CHD; ++j) {
            float hv = elu1(acc[j]);
            hblk[lane * HSTR + cbase + j] = hv;
            if (valid) hrow[j] = hv;
        }
    }
    __syncthreads();
    // ---- restage Wg0 ----
    for (int i = tid; i < HIDD * HIDD / 4; i += 256)
        ((float4*)Wl)[i] = ((const float4*)Wg0)[i];
    __syncthreads();

    // ---- stage 2: proj from LDS h ----
    const float* __restrict__ hr = &hblk[lane * HSTR];
    float acc[CHD] = {};
    for (int k0 = 0; k0 < HIDD; k0 += 2) {
        float2 hv = *(const float2*)(hr + k0);
        const float hvv[2] = {hv.x, hv.y};
#pragma unroll
        for (int kk = 0; kk < 2; ++kk) {
#pragma unroll
            for (int j4 = 0; j4 < CHD; j4 += 4) {
                float4 wv = *(const float4*)(&Wl[(k0 + kk) * HIDD + cbase + j4]);
                acc[j4 + 0] = fmaf(hvv[kk], wv.x, acc[j4 + 0]);
                acc[j4 + 1] = fmaf(hvv[kk], wv.y, acc[j4 + 1]);
                acc[j4 + 2] = fmaf(hvv[kk], wv.z, acc[j4 + 2]);
                acc[j4 + 3] = fmaf(hvv[kk], wv.w, acc[j4 + 3]);
            }
        }
    }
    if (valid) {
        unsigned* orow = hpb + (size_t)node * (HIDD / 2) + cbase / 2;
#pragma unroll
        for (int j = 0; j < CHD; j += 2)
            orow[j / 2] = (unsigned)f2bf(acc[j]) | ((unsigned)f2bf(acc[j + 1]) << 16);
        const float* __restrict__ s = asrc + head * CHD;
        const float* __restrict__ d = adst + head * CHD;
        float sa = 0.f, da = 0.f;
#pragma unroll
        for (int j = 0; j < CHD; ++j) { sa = fmaf(acc[j], s[j], sa); da = fmaf(acc[j], d[j], da); }
        as_[node * NHEAD + head] = sa;
        ad_[node * NHEAD + head] = da;
    }
}

// ---------------- per-layer proj (layers 1..3) ----------------

__global__ __launch_bounds__(256) void k_proj(const float* __restrict__ h,
                                              const float* __restrict__ W,
                                              const float* __restrict__ asrc,
                                              const float* __restrict__ adst,
                                              unsigned* __restrict__ hpb,   // [N][48] packed bf16x2
                                              float* __restrict__ as_,
                                              float* __restrict__ ad_) {
    __shared__ float Wl[HIDD * HIDD];   // 36 KB
    int tid = threadIdx.x;
    for (int i = tid; i < HIDD * HIDD / 4; i += 256)
        ((float4*)Wl)[i] = ((const float4*)W)[i];
    __syncthreads();

    int node = blockIdx.x * 64 + (tid & 63);
    if (node >= NODES) return;
    int head = tid >> 6;                 // 0..3 (wave-uniform)
    int cbase = head * CHD;
    const float* __restrict__ hr = h + (size_t)node * HIDD;

    float acc[CHD] = {};
    for (int k0 = 0; k0 < HIDD; k0 += 4) {
        float4 hv = *(const float4*)(hr + k0);
        const float hvv[4] = {hv.x, hv.y, hv.z, hv.w};
#pragma unroll
        for (int kk = 0; kk < 4; ++kk) {
#pragma unroll
            for (int j4 = 0; j4 < CHD; j4 += 4) {
                float4 wv = *(const float4*)(&Wl[(k0 + kk) * HIDD + cbase + j4]);
                acc[j4 + 0] = fmaf(hvv[kk], wv.x, acc[j4 + 0]);
                acc[j4 + 1] = fmaf(hvv[kk], wv.y, acc[j4 + 1]);
                acc[j4 + 2] = fmaf(hvv[kk], wv.z, acc[j4 + 2]);
                acc[j4 + 3] = fmaf(hvv[kk], wv.w, acc[j4 + 3]);
            }
        }
    }
    unsigned* orow = hpb + (size_t)node * (HIDD / 2) + cbase / 2;
#pragma unroll
    for (int j = 0; j < CHD; j += 2)
        orow[j / 2] = (unsigned)f2bf(acc[j]) | ((unsigned)f2bf(acc[j + 1]) << 16);

    const float* __restrict__ s = asrc + head * CHD;
    const float* __restrict__ d = adst + head * CHD;
    float sa = 0.f, da = 0.f;
#pragma unroll
    for (int j = 0; j < CHD; ++j) { sa = fmaf(acc[j], s[j], sa); da = fmaf(acc[j], d[j], da); }
    as_[node * NHEAD + head] = sa;
    ad_[node * NHEAD + head] = da;
}

// ---------------- fused edge phase: 2 nodes per wave, uniform-guarded chunks ----------------
// alpha = exp(leaky(as+ad)) / z (max-sub cancels in p/z; |ev| << 88, no overflow).

__global__ __launch_bounds__(256) void k_edge(const int* __restrict__ off,
                                              const int* __restrict__ csr,
                                              const float* __restrict__ as_,
                                              const float* __restrict__ ad_,
                                              const unsigned* __restrict__ hpb,
                                              const float* __restrict__ bg,
                                              const float* __restrict__ gamma,
                                              const float* __restrict__ beta,
                                              const float* __restrict__ rm,
                                              const float* __restrict__ rv,
                                              float* __restrict__ h,
                                              const int* __restrict__ batch,
                                              float* __restrict__ pooled) {
    __shared__ float plds[512];                     // per wave: 128 floats (2 nodes x 64)
    int tid = threadIdx.x;
    int lane = tid & 63;
    int n0 = __builtin_amdgcn_readfirstlane(blockIdx.x * 8 + (tid >> 6) * 2);  // exact grid
    int n1 = n0 + 1;
    int beg0 = off[n0], end0 = off[n0 + 1], end1 = off[n0 + 2];
    int beg1 = end0;                                // consecutive nodes share the boundary

    int hd = lane & 3, slot = lane >> 2;            // alpha role: edge slot x head
    float adv0 = ad_[n0 * NHEAD + hd];
    float adv1 = ad_[n1 * NHEAD + hd];
    const int hh = (lane < 48) ? (lane / 12) : 0;   // gather role: head of channel pair
    const bool gl = (lane < 48);
    const int wb = (tid & 192) * 2;                 // wave's plds region (w*128)

    float a00 = 0.f, a01 = 0.f, a10 = 0.f, a11 = 0.f, zA = 0.f, zB = 0.f;
    int ca = beg0, cb = beg1;
    while (ca < end0 || cb < end1) {
        int cntA = min(16, end0 - ca);              // wave-uniform chunk fills
        int cntB = min(16, end1 - cb);
        int sA = 0, sB = 0;
        if (cntA > 0) {
            int i = ca + slot, ii = min(i, end0 - 1);
            sA = csr[ii];
            float ev = as_[sA * NHEAD + hd] + adv0;
            ev = ev > 0.f ? ev : 0.2f * ev;
            float p = (i < end0) ? __expf(ev) : 0.f;
            zA += p;
            plds[wb + lane] = p;
        }
        if (cntB > 0) {
            int i = cb + slot, ii = min(i, end1 - 1);
            sB = csr[ii];
            float ev = as_[sB * NHEAD + hd] + adv1;
            ev = ev > 0.f ? ev : 0.2f * ev;
            float p = (i < end1) ? __expf(ev) : 0.f;
            zB += p;
            plds[wb + 64 + lane] = p;
        }
        if (cntA > 0) {
#pragma unroll
            for (int j = 0; j < 16; ++j) {
                if (j < cntA) {                     // wave-uniform guard: skip masked gathers
                    int sv = __builtin_amdgcn_readlane(sA, j * 4);
                    float al = plds[wb + j * 4 + hh];
                    if (gl) {
                        unsigned u = (hpb + (size_t)sv * (HIDD / 2))[lane];
                        a00 = fmaf(__uint_as_float(u << 16),         al, a00);
                        a01 = fmaf(__uint_as_float(u & 0xffff0000u), al, a01);
                    }
                }
            }
            ca += 16;
        }
        if (cntB > 0) {
#pragma unroll
            for (int j = 0; j < 16; ++j) {
                if (j < cntB) {
                    int sv = __builtin_amdgcn_readlane(sB, j * 4);
                    float al = plds[wb + 64 + j * 4 + hh];
                    if (gl) {
                        unsigned u = (hpb + (size_t)sv * (HIDD / 2))[lane];
                        a10 = fmaf(__uint_as_float(u << 16),         al, a10);
                        a11 = fmaf(__uint_as_float(u & 0xffff0000u), al, a11);
                    }
                }
            }
            cb += 16;
        }
    }
    // z totals per head for both nodes
#pragma unroll
    for (int o = 4; o < 64; o <<= 1) { zA += __shfl_xor(zA, o); zB += __shfl_xor(zB, o); }
    float za0 = rl_f(zA, 0), za1 = rl_f(zA, 1), za2 = rl_f(zA, 2), za3 = rl_f(zA, 3);
    float zb0 = rl_f(zB, 0), zb1 = rl_f(zB, 1), zb2 = rl_f(zB, 2), zb3 = rl_f(zB, 3);
    float zAl = (hh & 1) ? za1 : za0, zAh = (hh & 1) ? za3 : za2;
    float zBl = (hh & 1) ? zb1 : zb0, zBh = (hh & 1) ? zb3 : zb2;
    float zhA = (hh & 2) ? zAh : zAl;
    float zhB = (hh & 2) ? zBh : zBl;

    int g0 = batch[n0], g1 = batch[n1];             // uniform (s_load)
    if (gl) {
        float izA = 1.f / zhA, izB = 1.f / zhB;     // z > 0 guaranteed (self-loop)
        a00 *= izA; a01 *= izA; a10 *= izB; a11 *= izB;
        int ch0 = 2 * lane, ch1 = ch0 + 1;
        float hn00 = bnorm(a00, bg, rm, rv, gamma, beta, ch0);
        float hn01 = bnorm(a01, bg, rm, rv, gamma, beta, ch1);
        float hn10 = bnorm(a10, bg, rm, rv, gamma, beta, ch0);
        float hn11 = bnorm(a11, bg, rm, rv, gamma, beta, ch1);
        float2 hv0 = *(float2*)(h + (size_t)n0 * HIDD + ch0);
        float2 hv1 = *(float2*)(h + (size_t)n1 * HIDD + ch0);
        hv0.x += elu1(hn00); hv0.y += elu1(hn01);
        hv1.x += elu1(hn10); hv1.y += elu1(hn11);
        *(float2*)(h + (size_t)n0 * HIDD + ch0) = hv0;
        *(float2*)(h + (size_t)n1 * HIDD + ch0) = hv1;
        if (g0 == g1) {                             // merged pooled atomics (common: sorted batch)
            atomicAdd(&pooled[g0 * HIDD + ch0], hv0.x + hv1.x);
            atomicAdd(&pooled[g0 * HIDD + ch1], hv0.y + hv1.y);
        } else {
            atomicAdd(&pooled[g0 * HIDD + ch0], hv0.x);
            atomicAdd(&pooled[g0 * HIDD + ch1], hv0.y);
            atomicAdd(&pooled[g1 * HIDD + ch0], hv1.x);
            atomicAdd(&pooled[g1 * HIDD + ch1], hv1.y);
        }
    }
}

// ---------------- per-graph MLP head ----------------

__global__ __launch_bounds__(128) void k_head(const float* __restrict__ pooled,
                                              const float* __restrict__ Wjk, const float* __restrict__ bjk,
                                              const float* __restrict__ Wh1, const float* __restrict__ bh1,
                                              const float* __restrict__ Wh2, const float* __restrict__ bh2,
                                              float* __restrict__ out) {
    __shared__ float pin[NLAY * HIDD];
    __shared__ float z1[HIDD];
    __shared__ float z2[HIDD];
    int g = blockIdx.x, tid = threadIdx.x;
    for (int idx = tid; idx < NLAY * HIDD; idx += blockDim.x) {
        int l = idx / HIDD, c = idx % HIDD;
        pin[idx] = pooled[(size_t)l * NGRF * HIDD + (size_t)g * HIDD + c];
    }
    __syncthreads();
    for (int c = tid; c < HIDD; c += blockDim.x) {
        float a = bjk[c];
        for (int k = 0; k < NLAY * HIDD; ++k) a = fmaf(pin[k], Wjk[k * HIDD + c], a);
        z1[c] = elu1(a);
    }
    __syncthreads();
    for (int c = tid; c < HIDD; c += blockDim.x) {
        float a = bh1[c];
#pragma unroll
        for (int k = 0; k < HIDD; ++k) a = fmaf(z1[k], Wh1[k * HIDD + c], a);
        z2[c] = fmaxf(a, 0.f);
    }
    __syncthreads();
    if (tid < 64) {
        float a = 0.f;
        for (int k = tid; k < HIDD; k += 64) a = fmaf(z2[k], Wh2[k], a);
#pragma unroll
        for (int o = 32; o > 0; o >>= 1) a += __shfl_down(a, o);
        if (tid == 0) out[g] = a + bh2[0];
    }
}

extern "C" void kernel_launch(void* const* d_in, const int* in_sizes, int n_in,
                              void* d_out, int out_size, void* d_ws, size_t ws_size,
                              hipStream_t stream) {
    const float* x     = (const float*)d_in[0];
    const int*   ei    = (const int*)d_in[1];
    const int*   batch = (const int*)d_in[2];
    const float* W_in  = (const float*)d_in[3];
    const float* b_in  = (const float*)d_in[4];
    const float* Wg    = (const float*)d_in[5];
    const float* att_s = (const float*)d_in[6];
    const float* att_d = (const float*)d_in[7];
    const float* bg    = (const float*)d_in[8];
    const float* gamma = (const float*)d_in[9];
    const float* beta  = (const float*)d_in[10];
    const float* rm    = (const float*)d_in[11];
    const float* rv    = (const float*)d_in[12];
    const float* Wjk   = (const float*)d_in[13];
    const float* bjk   = (const float*)d_in[14];
    const float* Wh1   = (const float*)d_in[15];
    const float* bh1   = (const float*)d_in[16];
    const float* Wh2   = (const float*)d_in[17];
    const float* bh2   = (const float*)d_in[18];
    float* out = (float*)d_out;

    const int* S = ei;
    const int* Dd = ei + EDGES;

    // workspace layout
    float* ws = (float*)d_ws;
    float*    h      = ws;                               // N*96 f32
    float*    as_    = h    + (size_t)NODES * HIDD;      // N*4
    float*    ad_    = as_  + (size_t)NODES * NHEAD;     // N*4
    float*    pooled = ad_  + (size_t)NODES * NHEAD;     // L*G*96
    unsigned* hpb    = (unsigned*)(pooled + (size_t)NLAY * NGRF * HIDD); // N*48 (bf16x2)
    int*      off    = (int*)(hpb + (size_t)NODES * (HIDD / 2));  // N+2
    int*      cursor = off    + NODES + 2;               // N
    int*      csr    = cursor + NODES;                   // EP
    int*      cnt    = csr    + EP;                      // N
    int*      bsum   = cnt    + NODES;                   // NB

    hipMemsetAsync(pooled, 0, sizeof(float) * NLAY * NGRF * HIDD, stream);
    hipMemsetAsync(cnt, 0, sizeof(int) * NODES, stream);

    const int TB = 256;
    int gE    = (EP + TB - 1) / TB;
    int gTile = (NODES + 63) / 64;   // 782 blocks, 64 nodes each
    int gEdge = NODES / 8;           // 6250 (exact: 8 nodes/block, 2 per wave)

    // CSR build (graph is identical across layers)
    k_count<<<gE, TB, 0, stream>>>(S, Dd, cnt);
    k_scan1<<<NB, 1024, 0, stream>>>(cnt, off, bsum);
    k_scan3m<<<NB, 1024, 0, stream>>>(off, bsum, cursor);
    k_scatter<<<gE, TB, 0, stream>>>(S, Dd, cursor, csr);

    // layer 0: fused input-proj + proj
    k_in_proj_proj<<<gTile, TB, 0, stream>>>(x, W_in, b_in, Wg, att_s, att_d,
                                             h, hpb, as_, ad_);
    k_edge<<<gEdge, TB, 0, stream>>>(off, csr, as_, ad_, hpb,
                                     bg, gamma, beta, rm, rv, h, batch, pooled);

    for (int i = 1; i < NLAY; ++i) {
        k_proj<<<gTile, TB, 0, stream>>>(h, Wg + (size_t)i * HIDD * HIDD,
                                         att_s + i * NHEAD * CHD, att_d + i * NHEAD * CHD,
                                         hpb, as_, ad_);
        k_edge<<<gEdge, TB, 0, stream>>>(off, csr, as_, ad_, hpb,
                                         bg + i * HIDD, gamma + i * HIDD, beta + i * HIDD,
                                         rm + i * HIDD, rv + i * HIDD, h, batch,
                                         pooled + (size_t)i * NGRF * HIDD);
    }

    k_head<<<NGRF, 128, 0, stream>>>(pooled, Wjk, bjk, Wh1, bh1, Wh2, bh2, out);
}